// Round 1
// baseline (682.656 us; speedup 1.0000x reference)
//
#include <hip/hip_runtime.h>

// DiffAttn on MI355X.
// Pipeline: cvt X->bf16 ; W->W^T bf16 ; NT-GEMMs for Q,K,V^T ; NT-GEMMs for
// S1,S2 (bf16 to ws, fused partial softmax stats) ; stats reduce ; apply
// (P = softmax1 - lam*softmax2, PV via MFMA, fp32 out).

typedef unsigned short u16;
typedef short    bf16x8 __attribute__((ext_vector_type(8)));
typedef unsigned short u16x8 __attribute__((ext_vector_type(8)));
typedef unsigned short u16x4 __attribute__((ext_vector_type(4)));
typedef float    f32x4  __attribute__((ext_vector_type(4)));

typedef __attribute__((address_space(3))) unsigned int       lds_uint;
typedef __attribute__((address_space(1))) const unsigned int gl_uint;

__device__ __forceinline__ void glds16(const void* g, void* l) {
  // 16B per lane, global -> LDS DMA. LDS dest = wave-uniform base + lane*16.
  __builtin_amdgcn_global_load_lds((gl_uint*)g, (lds_uint*)l, 16, 0, 0);
}

__device__ __forceinline__ u16 to_bf16(float f) {
  unsigned u = __float_as_uint(f);
  return (u16)((u + 0x7FFFu + ((u >> 16) & 1u)) >> 16);  // RNE
}
__device__ __forceinline__ float b2f(u16 h) {
  return __uint_as_float(((unsigned)h) << 16);
}

// ---------------- conversion kernels ----------------

__global__ void cvt_x(const float4* __restrict__ in, u16x4* __restrict__ out, int n4) {
  int i = blockIdx.x * 256 + threadIdx.x;
  if (i >= n4) return;
  float4 v = in[i];
  u16x4 o;
  o[0] = to_bf16(v.x); o[1] = to_bf16(v.y); o[2] = to_bf16(v.z); o[3] = to_bf16(v.w);
  out[i] = o;
}

// out[c][r] = bf16(in[r][c]); R,C multiples of 64. block (64,4).
__global__ void transpose_cvt(const float* __restrict__ in, u16* __restrict__ out,
                              int R, int C) {
  __shared__ float t[64][65];
  int c0 = blockIdx.x * 64, r0 = blockIdx.y * 64;
  int tx = threadIdx.x, ty = threadIdx.y;
  #pragma unroll
  for (int i = 0; i < 64; i += 4)
    t[ty + i][tx] = in[(long)(r0 + ty + i) * C + c0 + tx];
  __syncthreads();
  #pragma unroll
  for (int i = 0; i < 64; i += 4)
    out[(long)(c0 + ty + i) * R + r0 + tx] = to_bf16(t[tx][ty + i]);
}

// ---------------- NT GEMM: C[m][n] = scale * sum_k A[m][k]*B[n][k] (+bias) ----------------
// 128x128 tile, BK=64, 256 threads = 4 waves (2x2, each 64x64 = 16 MFMA tiles).
// LDS layout per operand: [mg=row/8][c=k/8][ml=row%8][8 elems]; this is exactly
// contiguous for glds16 (lane = c*8+ml) and 2-way-only on ds_read_b128 frag reads.
// Optional fused softmax stats: per row, per 64-col block: (max, sumexp) -> statsP.
__global__ __launch_bounds__(256) void gemm_nt(
    const u16* __restrict__ A, int lda, long long aStr,
    const u16* __restrict__ B, int ldb, long long bStr,
    u16* __restrict__ C, int ldc, long long cStr,
    int Kd, float scale,
    const float* __restrict__ bias, int biasMode,   // 0 none, 1 per-col, 2 per-row
    float* __restrict__ statsP)
{
  int bz = blockIdx.z;
  A += (long)bz * aStr; B += (long)bz * bStr; C += (long)bz * cStr;
  if (statsP) statsP += (long)bz * 262144;  // [b][half][row][kb][2], half pre-offset by host

  __shared__ u16 As[128 * 64];
  __shared__ u16 Bs[128 * 64];

  int tid = threadIdx.x;
  int wave = tid >> 6, lane = tid & 63;
  int quad = lane >> 4, ln = lane & 15;
  int wm = wave >> 1, wn = wave & 1;
  int tm = blockIdx.y, tn = blockIdx.x;
  int c8 = lane >> 3, ml = lane & 7;

  const f32x4 fz = {0.f, 0.f, 0.f, 0.f};
  f32x4 acc[4][4];
  #pragma unroll
  for (int i = 0; i < 4; i++)
    #pragma unroll
    for (int j = 0; j < 4; j++) acc[i][j] = fz;

  const u16* Abase = A + (long)(tm * 128 + ml) * lda + c8 * 8;
  const u16* Bbase = B + (long)(tn * 128 + ml) * ldb + c8 * 8;

  for (int kt = 0; kt < Kd; kt += 64) {
    __syncthreads();
    #pragma unroll
    for (int i = 0; i < 4; i++) {
      int mg = wave * 4 + i;
      glds16(Abase + (long)mg * 8 * lda + kt, &As[mg * 512]);
      glds16(Bbase + (long)mg * 8 * ldb + kt, &Bs[mg * 512]);
    }
    __syncthreads();
    #pragma unroll
    for (int ks = 0; ks < 2; ks++) {
      bf16x8 af[4], bfr[4];
      int c = ks * 4 + quad;
      #pragma unroll
      for (int mt = 0; mt < 4; mt++) {
        int m = wm * 64 + mt * 16 + ln;
        af[mt] = *(const bf16x8*)&As[((m >> 3) * 64 + c * 8 + (m & 7)) * 8];
      }
      #pragma unroll
      for (int nt = 0; nt < 4; nt++) {
        int n = wn * 64 + nt * 16 + ln;
        bfr[nt] = *(const bf16x8*)&Bs[((n >> 3) * 64 + c * 8 + (n & 7)) * 8];
      }
      #pragma unroll
      for (int mt = 0; mt < 4; mt++)
        #pragma unroll
        for (int nt = 0; nt < 4; nt++)
          acc[mt][nt] = __builtin_amdgcn_mfma_f32_16x16x32_bf16(af[mt], bfr[nt], acc[mt][nt], 0, 0, 0);
    }
  }

  int rowBase = tm * 128 + wm * 64;
  int colBase = tn * 128 + wn * 64;
  #pragma unroll
  for (int mt = 0; mt < 4; mt++) {
    #pragma unroll
    for (int nt = 0; nt < 4; nt++) {
      int col = colBase + nt * 16 + ln;
      float bcol = (biasMode == 1) ? bias[col] : 0.f;
      #pragma unroll
      for (int r = 0; r < 4; r++) {
        int row = rowBase + mt * 16 + quad * 4 + r;
        float brow = (biasMode == 2) ? bias[row] : 0.f;
        float v = acc[mt][nt][r] * scale + bcol + brow;
        C[(long)row * ldc + col] = to_bf16(v);
      }
    }
  }

  if (statsP) {
    #pragma unroll
    for (int mt = 0; mt < 4; mt++) {
      #pragma unroll
      for (int r = 0; r < 4; r++) {
        float v0 = acc[mt][0][r] * scale;
        float v1 = acc[mt][1][r] * scale;
        float v2 = acc[mt][2][r] * scale;
        float v3 = acc[mt][3][r] * scale;
        float mx = fmaxf(fmaxf(v0, v1), fmaxf(v2, v3));
        #pragma unroll
        for (int d = 1; d < 16; d <<= 1) mx = fmaxf(mx, __shfl_xor(mx, d, 64));
        float sm = __expf(v0 - mx) + __expf(v1 - mx) + __expf(v2 - mx) + __expf(v3 - mx);
        #pragma unroll
        for (int d = 1; d < 16; d <<= 1) sm += __shfl_xor(sm, d, 64);
        if (ln == 0) {
          int row = rowBase + mt * 16 + quad * 4 + r;
          int kb = tn * 2 + wn;             // 64-col blocks, 32 total
          statsP[((long)row * 32 + kb) * 2]     = mx;
          statsP[((long)row * 32 + kb) * 2 + 1] = sm;
        }
      }
    }
  }
}

// ---------------- stats reduce: 32 partials -> (m, l) per row/half ----------------
__global__ void stats_reduce(const float* __restrict__ sp, float* __restrict__ so) {
  int gid = blockIdx.x * 256 + threadIdx.x;   // 0..32767 = (b*2+half)*2048+row
  const float* p = sp + (long)gid * 64;
  float M = -1e30f;
  #pragma unroll
  for (int kb = 0; kb < 32; kb++) M = fmaxf(M, p[kb * 2]);
  float L = 0.f;
  #pragma unroll
  for (int kb = 0; kb < 32; kb++) L += p[kb * 2 + 1] * __expf(p[kb * 2] - M);
  so[(long)gid * 2]     = M;
  so[(long)gid * 2 + 1] = L;
}

// ---------------- apply: O = (softmax(S1) - lam*softmax(S2)) @ V ----------------
// grid (qt=32, b=8), 256 threads = 4 waves. Block owns 64 q rows x all keys.
// Wave w owns d-slice [w*128, w*128+128). Per 64-key tile: P tile bf16 in LDS
// (A-operand layout, +8 pad), V^T tile staged via glds16 in chunk-swizzled layout.
__global__ __launch_bounds__(256) void apply_pv(
    const u16* __restrict__ S1, const u16* __restrict__ S2,
    const u16* __restrict__ VT, const float* __restrict__ stats,
    const float* __restrict__ lamPtr, float* __restrict__ Out)
{
  __shared__ u16 Ps[64 * 72];
  __shared__ u16 Vs[512 * 64];
  __shared__ float m1s[64], i1s[64], m2s[64], i2s[64];

  int b = blockIdx.y, qt = blockIdx.x;
  int q0 = qt * 64;
  int tid = threadIdx.x;
  int wave = tid >> 6, lane = tid & 63, quad = lane >> 4, ln = lane & 15;
  float lam = lamPtr[0];

  if (tid < 64) {
    long idx = ((long)(b * 2 + 0) * 2048 + q0 + tid) * 2;
    m1s[tid] = stats[idx];
    i1s[tid] = 1.0f / stats[idx + 1];
  } else if (tid < 128) {
    int r = tid - 64;
    long idx = ((long)(b * 2 + 1) * 2048 + q0 + r) * 2;
    m2s[r] = stats[idx];
    i2s[r] = 1.0f / stats[idx + 1];
  }

  const f32x4 fz = {0.f, 0.f, 0.f, 0.f};
  f32x4 acc[4][8];
  #pragma unroll
  for (int mt = 0; mt < 4; mt++)
    #pragma unroll
    for (int nt = 0; nt < 8; nt++) acc[mt][nt] = fz;

  int d0 = wave * 128;
  int c8 = lane >> 3, ml = lane & 7;
  int r = tid >> 2, cg = (tid & 3) * 16;
  const u16* s1p = S1 + ((long)b * 2048 + q0 + r) * 2048 + cg;
  const u16* s2p = S2 + ((long)b * 2048 + q0 + r) * 2048 + cg;
  float m1 = 0.f, i1 = 0.f, m2 = 0.f, i2 = 0.f;

  for (int kt = 0; kt < 2048; kt += 64) {
    __syncthreads();
    // stage V^T d-slice for this wave: rows wave*128..+128, cols kt..kt+64
    #pragma unroll
    for (int i = 0; i < 16; i++) {
      int dg = wave * 16 + i;
      glds16(VT + (long)(dg * 8 + ml) * 16384 + b * 2048 + kt + c8 * 8, &Vs[dg * 512]);
    }
    if (kt == 0) { m1 = m1s[r]; i1 = i1s[r]; m2 = m2s[r]; i2 = i2s[r]; }
    // P tile: each thread does 16 cols of row r
    u16x8 a1 = *(const u16x8*)(s1p + kt);
    u16x8 b1 = *(const u16x8*)(s1p + kt + 8);
    u16x8 a2 = *(const u16x8*)(s2p + kt);
    u16x8 b2 = *(const u16x8*)(s2p + kt + 8);
    u16x8 o1, o2;
    #pragma unroll
    for (int j = 0; j < 8; j++) {
      float p = __expf(b2f(a1[j]) - m1) * i1 - lam * __expf(b2f(a2[j]) - m2) * i2;
      o1[j] = to_bf16(p);
      float q = __expf(b2f(b1[j]) - m1) * i1 - lam * __expf(b2f(b2[j]) - m2) * i2;
      o2[j] = to_bf16(q);
    }
    *(u16x8*)&Ps[r * 72 + cg]     = o1;
    *(u16x8*)&Ps[r * 72 + cg + 8] = o2;
    __syncthreads();

    #pragma unroll
    for (int ks = 0; ks < 2; ks++) {
      bf16x8 pf[4], vf[8];
      int c = ks * 4 + quad;
      #pragma unroll
      for (int mt = 0; mt < 4; mt++)
        pf[mt] = *(const bf16x8*)&Ps[(mt * 16 + ln) * 72 + ks * 32 + quad * 8];
      #pragma unroll
      for (int nt = 0; nt < 8; nt++) {
        int d = d0 + nt * 16 + ln;
        vf[nt] = *(const bf16x8*)&Vs[((d >> 3) * 64 + c * 8 + (d & 7)) * 8];
      }
      #pragma unroll
      for (int mt = 0; mt < 4; mt++)
        #pragma unroll
        for (int nt = 0; nt < 8; nt++)
          acc[mt][nt] = __builtin_amdgcn_mfma_f32_16x16x32_bf16(pf[mt], vf[nt], acc[mt][nt], 0, 0, 0);
    }
  }

  #pragma unroll
  for (int mt = 0; mt < 4; mt++)
    #pragma unroll
    for (int nt = 0; nt < 8; nt++)
      #pragma unroll
      for (int r2 = 0; r2 < 4; r2++)
        Out[((long)b * 2048 + q0 + mt * 16 + quad * 4 + r2) * 512 + d0 + nt * 16 + ln] =
            acc[mt][nt][r2];
}

// ---------------- launch ----------------

extern "C" void kernel_launch(void* const* d_in, const int* in_sizes, int n_in,
                              void* d_out, int out_size, void* d_ws, size_t ws_size,
                              hipStream_t stream)
{
  const float* X   = (const float*)d_in[0];
  const float* lam = (const float*)d_in[1];
  const float* Wq  = (const float*)d_in[2];
  const float* bq  = (const float*)d_in[3];
  const float* Wk  = (const float*)d_in[4];
  const float* bk  = (const float*)d_in[5];
  const float* Wv  = (const float*)d_in[6];
  const float* bv  = (const float*)d_in[7];
  float* Out = (float*)d_out;
  char* ws = (char*)d_ws;

  // workspace layout (bytes); Xb overlaps S1 (Xb dead before S1 written)
  u16* WqT = (u16*)(ws + 0);           //  2 MB [1024][1024]
  u16* WkT = (u16*)(ws + 2097152);     //  2 MB
  u16* WvT = (u16*)(ws + 4194304);     //  1 MB [512][1024]
  u16* Qb  = (u16*)(ws + 5242880);     // 32 MB [16384][1024]
  u16* Kb  = (u16*)(ws + 38797312);    // 32 MB
  u16* VTb = (u16*)(ws + 72351744);    // 16 MB [512][16384]
  u16* S1  = (u16*)(ws + 89128960);    // 64 MB [8][2048][2048]
  u16* Xb  = S1;                       // 32 MB overlap [16384][1024]
  u16* S2  = (u16*)(ws + 156237824);   // 64 MB
  float* statsP = (float*)(ws + 223346688); // 16 MB [8][2][2048][32][2]
  float* statsF = (float*)(ws + 240123904); // 256 KB [8][2][2048][2]

  cvt_x<<<16384, 256, 0, stream>>>((const float4*)X, (u16x4*)Xb, 4194304);
  transpose_cvt<<<dim3(16, 16), dim3(64, 4), 0, stream>>>(Wq, WqT, 1024, 1024);
  transpose_cvt<<<dim3(16, 16), dim3(64, 4), 0, stream>>>(Wk, WkT, 1024, 1024);
  transpose_cvt<<<dim3(8, 16),  dim3(64, 4), 0, stream>>>(Wv, WvT, 1024, 512);

  // Q = Xb @ WqT^T + bq ; K likewise
  gemm_nt<<<dim3(8, 128, 1), 256, 0, stream>>>(Xb, 1024, 0LL, WqT, 1024, 0LL,
                                               Qb, 1024, 0LL, 1024, 1.0f, bq, 1, nullptr);
  gemm_nt<<<dim3(8, 128, 1), 256, 0, stream>>>(Xb, 1024, 0LL, WkT, 1024, 0LL,
                                               Kb, 1024, 0LL, 1024, 1.0f, bk, 1, nullptr);
  // V^T[d][m] = sum_e WvT[d][e]*Xb[m][e] + bv[d]
  gemm_nt<<<dim3(128, 4, 1), 256, 0, stream>>>(WvT, 1024, 0LL, Xb, 1024, 0LL,
                                               VTb, 16384, 0LL, 1024, 1.0f, bv, 2, nullptr);

  const float s = 0.044194173824159216f;  // 1/sqrt(512)
  // S1[q][k] = s * Q1[q].K1[k] ; fused partial stats
  gemm_nt<<<dim3(16, 16, 8), 256, 0, stream>>>(Qb, 1024, 2097152LL, Kb, 1024, 2097152LL,
                                               S1, 2048, 4194304LL, 512, s,
                                               nullptr, 0, statsP);
  gemm_nt<<<dim3(16, 16, 8), 256, 0, stream>>>(Qb + 512, 1024, 2097152LL, Kb + 512, 1024, 2097152LL,
                                               S2, 2048, 4194304LL, 512, s,
                                               nullptr, 0, statsP + 131072);

  stats_reduce<<<128, 256, 0, stream>>>(statsP, statsF);
  apply_pv<<<dim3(32, 8), 256, 0, stream>>>(S1, S2, VTb, statsF, lam, Out);
}

// Round 2
// 657.827 us; speedup vs baseline: 1.0377x; 1.0377x over previous
//
#include <hip/hip_runtime.h>

// DiffAttn on MI355X, round 2.
// cvt X->bf16 ; W->W^T bf16 (Wq,Wk concat) ; one NT-GEMM for [Q|K], one for
// V^T ; NT-GEMMs for S1,S2 (bf16, no fused stats) ; memory-bound row-stats
// pass ; apply (P = softmax1 - lam*softmax2, PV via MFMA, fp32 out).

typedef unsigned short u16;
typedef short    bf16x8 __attribute__((ext_vector_type(8)));
typedef unsigned short u16x8 __attribute__((ext_vector_type(8)));
typedef unsigned short u16x4 __attribute__((ext_vector_type(4)));
typedef float    f32x4  __attribute__((ext_vector_type(4)));

typedef __attribute__((address_space(3))) unsigned int       lds_uint;
typedef __attribute__((address_space(1))) const unsigned int gl_uint;

__device__ __forceinline__ void glds16(const void* g, void* l) {
  // 16B per lane, global -> LDS DMA. LDS dest = wave-uniform base + lane*16.
  __builtin_amdgcn_global_load_lds((gl_uint*)g, (lds_uint*)l, 16, 0, 0);
}

__device__ __forceinline__ u16 to_bf16(float f) {
  unsigned u = __float_as_uint(f);
  return (u16)((u + 0x7FFFu + ((u >> 16) & 1u)) >> 16);  // RNE
}
__device__ __forceinline__ float b2f(u16 h) {
  return __uint_as_float(((unsigned)h) << 16);
}

// ---------------- conversion kernels ----------------

__global__ void cvt_x(const float4* __restrict__ in, u16x4* __restrict__ out, int n4) {
  int i = blockIdx.x * 256 + threadIdx.x;
  if (i >= n4) return;
  float4 v = in[i];
  u16x4 o;
  o[0] = to_bf16(v.x); o[1] = to_bf16(v.y); o[2] = to_bf16(v.z); o[3] = to_bf16(v.w);
  out[i] = o;
}

// out[c][r] = bf16(in[r][c]); R,C multiples of 64. block (64,4).
__global__ void transpose_cvt(const float* __restrict__ in, u16* __restrict__ out,
                              int R, int C) {
  __shared__ float t[64][65];
  int c0 = blockIdx.x * 64, r0 = blockIdx.y * 64;
  int tx = threadIdx.x, ty = threadIdx.y;
  #pragma unroll
  for (int i = 0; i < 64; i += 4)
    t[ty + i][tx] = in[(long)(r0 + ty + i) * C + c0 + tx];
  __syncthreads();
  #pragma unroll
  for (int i = 0; i < 64; i += 4)
    out[(long)(c0 + ty + i) * R + r0 + tx] = to_bf16(t[tx][ty + i]);
}

__global__ void concat2(const float* __restrict__ a, const float* __restrict__ b,
                        float* __restrict__ o, int n) {
  int i = blockIdx.x * 256 + threadIdx.x;
  if (i < n) o[i] = a[i];
  else if (i < 2 * n) o[i] = b[i - n];
}

// ---------------- NT GEMM: C[m][n] = scale * sum_k A[m][k]*B[n][k] (+bias) ----------------
// 128x128 tile, BK=64, 256 threads = 4 waves (2x2, each 64x64 = 16 MFMA tiles).
// LDS layout per operand: [mg=row/8][c=k/8][ml=row%8][8 elems]; contiguous for
// glds16 (lane = c*8+ml) and 2-way-only conflicts on ds_read_b128 frag reads.
__global__ __launch_bounds__(256) void gemm_nt(
    const u16* __restrict__ A, int lda, long long aStr,
    const u16* __restrict__ B, int ldb, long long bStr,
    u16* __restrict__ C, int ldc, long long cStr,
    int Kd, float scale,
    const float* __restrict__ bias, int biasMode)   // 0 none, 1 per-col, 2 per-row
{
  int bz = blockIdx.z;
  A += (long)bz * aStr; B += (long)bz * bStr; C += (long)bz * cStr;

  __shared__ u16 As[128 * 64];
  __shared__ u16 Bs[128 * 64];

  int tid = threadIdx.x;
  int wave = tid >> 6, lane = tid & 63;
  int quad = lane >> 4, ln = lane & 15;
  int wm = wave >> 1, wn = wave & 1;
  int tm = blockIdx.y, tn = blockIdx.x;
  int c8 = lane >> 3, ml = lane & 7;

  const f32x4 fz = {0.f, 0.f, 0.f, 0.f};
  f32x4 acc[4][4];
  #pragma unroll
  for (int i = 0; i < 4; i++)
    #pragma unroll
    for (int j = 0; j < 4; j++) acc[i][j] = fz;

  const u16* Abase = A + (long)(tm * 128 + ml) * lda + c8 * 8;
  const u16* Bbase = B + (long)(tn * 128 + ml) * ldb + c8 * 8;

  for (int kt = 0; kt < Kd; kt += 64) {
    __syncthreads();
    #pragma unroll
    for (int i = 0; i < 4; i++) {
      int mg = wave * 4 + i;
      glds16(Abase + (long)mg * 8 * lda + kt, &As[mg * 512]);
      glds16(Bbase + (long)mg * 8 * ldb + kt, &Bs[mg * 512]);
    }
    __syncthreads();
    #pragma unroll
    for (int ks = 0; ks < 2; ks++) {
      bf16x8 af[4], bfr[4];
      int c = ks * 4 + quad;
      #pragma unroll
      for (int mt = 0; mt < 4; mt++) {
        int m = wm * 64 + mt * 16 + ln;
        af[mt] = *(const bf16x8*)&As[((m >> 3) * 64 + c * 8 + (m & 7)) * 8];
      }
      #pragma unroll
      for (int nt = 0; nt < 4; nt++) {
        int n = wn * 64 + nt * 16 + ln;
        bfr[nt] = *(const bf16x8*)&Bs[((n >> 3) * 64 + c * 8 + (n & 7)) * 8];
      }
      #pragma unroll
      for (int mt = 0; mt < 4; mt++)
        #pragma unroll
        for (int nt = 0; nt < 4; nt++)
          acc[mt][nt] = __builtin_amdgcn_mfma_f32_16x16x32_bf16(af[mt], bfr[nt], acc[mt][nt], 0, 0, 0);
    }
  }

  int rowBase = tm * 128 + wm * 64;
  int colBase = tn * 128 + wn * 64;
  #pragma unroll
  for (int mt = 0; mt < 4; mt++) {
    #pragma unroll
    for (int nt = 0; nt < 4; nt++) {
      int col = colBase + nt * 16 + ln;
      float bcol = (biasMode == 1) ? bias[col] : 0.f;
      #pragma unroll
      for (int r = 0; r < 4; r++) {
        int row = rowBase + mt * 16 + quad * 4 + r;
        float brow = (biasMode == 2) ? bias[row] : 0.f;
        float v = acc[mt][nt][r] * scale + bcol + brow;
        C[(long)row * ldc + col] = to_bf16(v);
      }
    }
  }
}

// ---------------- row stats: per row of S1/S2, (max, sumexp) ----------------
// One wave per row (2048 bf16 cols, 32 per lane). Memory-bound.
__global__ __launch_bounds__(256) void row_stats(const u16* __restrict__ S1,
                                                 const u16* __restrict__ S2,
                                                 float* __restrict__ so) {
  int wid = blockIdx.x * 4 + (threadIdx.x >> 6);  // 0..32767
  int lane = threadIdx.x & 63;
  int arr = wid >> 14;                            // 0: S1, 1: S2
  int row = wid & 16383;                          // b*2048 + s
  const u16* p = (arr ? S2 : S1) + (long)row * 2048 + lane * 8;
  float v[32];
  #pragma unroll
  for (int i = 0; i < 4; i++) {
    u16x8 x = *(const u16x8*)(p + i * 512);
    #pragma unroll
    for (int j = 0; j < 8; j++) v[i * 8 + j] = b2f(x[j]);
  }
  float M = v[0];
  #pragma unroll
  for (int i = 1; i < 32; i++) M = fmaxf(M, v[i]);
  #pragma unroll
  for (int d = 1; d < 64; d <<= 1) M = fmaxf(M, __shfl_xor(M, d, 64));
  float L = 0.f;
  #pragma unroll
  for (int i = 0; i < 32; i++) L += __expf(v[i] - M);
  #pragma unroll
  for (int d = 1; d < 64; d <<= 1) L += __shfl_xor(L, d, 64);
  if (lane == 0) {
    int b = row >> 11, s = row & 2047;
    long idx = ((long)b * 2 + arr) * 2048 + s;
    so[idx * 2]     = M;
    so[idx * 2 + 1] = L;
  }
}

// ---------------- apply: O = (softmax(S1) - lam*softmax(S2)) @ V ----------------
// grid (qt=64, b=8) -> 512 blocks (~2/CU), 256 threads = 4 waves. Block owns
// 32 q rows x all keys; wave w owns d-slice [w*128, w*128+128).
__global__ __launch_bounds__(256) void apply_pv(
    const u16* __restrict__ S1, const u16* __restrict__ S2,
    const u16* __restrict__ VT, const float* __restrict__ stats,
    const float* __restrict__ lamPtr, float* __restrict__ Out)
{
  __shared__ u16 Ps[32 * 72];
  __shared__ u16 Vs[512 * 64];
  __shared__ float m1s[32], i1s[32], m2s[32], i2s[32];

  int b = blockIdx.y, qt = blockIdx.x;
  int q0 = qt * 32;
  int tid = threadIdx.x;
  int wave = tid >> 6, lane = tid & 63, quad = lane >> 4, ln = lane & 15;
  float lam = lamPtr[0];

  if (tid < 32) {
    long idx = ((long)(b * 2 + 0) * 2048 + q0 + tid) * 2;
    m1s[tid] = stats[idx];
    i1s[tid] = 1.0f / stats[idx + 1];
  } else if (tid < 64) {
    int r = tid - 32;
    long idx = ((long)(b * 2 + 1) * 2048 + q0 + r) * 2;
    m2s[r] = stats[idx];
    i2s[r] = 1.0f / stats[idx + 1];
  }

  const f32x4 fz = {0.f, 0.f, 0.f, 0.f};
  f32x4 acc[2][8];
  #pragma unroll
  for (int mt = 0; mt < 2; mt++)
    #pragma unroll
    for (int nt = 0; nt < 8; nt++) acc[mt][nt] = fz;

  int d0 = wave * 128;
  int c8 = lane >> 3, ml = lane & 7;
  int r = tid >> 3, cg = (tid & 7) * 8;
  const u16* s1p = S1 + ((long)b * 2048 + q0 + r) * 2048 + cg;
  const u16* s2p = S2 + ((long)b * 2048 + q0 + r) * 2048 + cg;
  float m1 = 0.f, i1 = 0.f, m2 = 0.f, i2 = 0.f;

  for (int kt = 0; kt < 2048; kt += 64) {
    __syncthreads();
    // stage V^T d-slice for this wave: rows wave*128..+128, cols kt..kt+64
    #pragma unroll
    for (int i = 0; i < 16; i++) {
      int dg = wave * 16 + i;
      glds16(VT + (long)(dg * 8 + ml) * 16384 + b * 2048 + kt + c8 * 8, &Vs[dg * 512]);
    }
    if (kt == 0) { m1 = m1s[r]; i1 = i1s[r]; m2 = m2s[r]; i2 = i2s[r]; }
    // P tile: each thread does 8 cols of row r
    u16x8 a1 = *(const u16x8*)(s1p + kt);
    u16x8 a2 = *(const u16x8*)(s2p + kt);
    u16x8 o1;
    #pragma unroll
    for (int j = 0; j < 8; j++) {
      float p = __expf(b2f(a1[j]) - m1) * i1 - lam * __expf(b2f(a2[j]) - m2) * i2;
      o1[j] = to_bf16(p);
    }
    *(u16x8*)&Ps[r * 72 + cg] = o1;
    __syncthreads();

    #pragma unroll
    for (int ks = 0; ks < 2; ks++) {
      bf16x8 pf[2], vf[8];
      int c = ks * 4 + quad;
      #pragma unroll
      for (int mt = 0; mt < 2; mt++)
        pf[mt] = *(const bf16x8*)&Ps[(mt * 16 + ln) * 72 + ks * 32 + quad * 8];
      #pragma unroll
      for (int nt = 0; nt < 8; nt++) {
        int d = d0 + nt * 16 + ln;
        vf[nt] = *(const bf16x8*)&Vs[((d >> 3) * 64 + c * 8 + (d & 7)) * 8];
      }
      #pragma unroll
      for (int mt = 0; mt < 2; mt++)
        #pragma unroll
        for (int nt = 0; nt < 8; nt++)
          acc[mt][nt] = __builtin_amdgcn_mfma_f32_16x16x32_bf16(pf[mt], vf[nt], acc[mt][nt], 0, 0, 0);
    }
  }

  #pragma unroll
  for (int mt = 0; mt < 2; mt++)
    #pragma unroll
    for (int nt = 0; nt < 8; nt++)
      #pragma unroll
      for (int r2 = 0; r2 < 4; r2++)
        Out[((long)b * 2048 + q0 + mt * 16 + quad * 4 + r2) * 512 + d0 + nt * 16 + ln] =
            acc[mt][nt][r2];
}

// ---------------- launch ----------------

extern "C" void kernel_launch(void* const* d_in, const int* in_sizes, int n_in,
                              void* d_out, int out_size, void* d_ws, size_t ws_size,
                              hipStream_t stream)
{
  const float* X   = (const float*)d_in[0];
  const float* lam = (const float*)d_in[1];
  const float* Wq  = (const float*)d_in[2];
  const float* bq  = (const float*)d_in[3];
  const float* Wk  = (const float*)d_in[4];
  const float* bk  = (const float*)d_in[5];
  const float* Wv  = (const float*)d_in[6];
  const float* bv  = (const float*)d_in[7];
  float* Out = (float*)d_out;
  char* ws = (char*)d_ws;

  // workspace layout (bytes); Xb overlaps S1 (Xb dead before S1 written)
  u16*  WqkT   = (u16*)(ws + 0);           //  4 MB [2048][1024] (rows 0..1023 = Wq^T, 1024.. = Wk^T)
  u16*  WvT    = (u16*)(ws + 4194304);     //  1 MB [512][1024]
  float* bqk   = (float*)(ws + 5242880);   //  8 KB [2048]
  u16*  QKb    = (u16*)(ws + 6291456);     // 64 MB [16384][2048]  (cols: Q1 Q2 K1 K2)
  u16*  VTb    = (u16*)(ws + 73400320);    // 16 MB [512][16384]
  u16*  Xb     = (u16*)(ws + 90177536);    // 32 MB [16384][1024]
  u16*  S1     = (u16*)(ws + 90177536);    // 64 MB overlap with Xb
  u16*  S2     = (u16*)(ws + 157286400);   // 64 MB
  float* statsF= (float*)(ws + 224395264); // 256 KB [8][2][2048][2]

  cvt_x<<<16384, 256, 0, stream>>>((const float4*)X, (u16x4*)Xb, 4194304);
  transpose_cvt<<<dim3(16, 16), dim3(64, 4), 0, stream>>>(Wq, WqkT, 1024, 1024);
  transpose_cvt<<<dim3(16, 16), dim3(64, 4), 0, stream>>>(Wk, WqkT + 1024 * 1024, 1024, 1024);
  transpose_cvt<<<dim3(8, 16),  dim3(64, 4), 0, stream>>>(Wv, WvT, 1024, 512);
  concat2<<<8, 256, 0, stream>>>(bq, bk, bqk, 1024);

  // [Q|K] = Xb @ WqkT^T + bqk
  gemm_nt<<<dim3(16, 128, 1), 256, 0, stream>>>(Xb, 1024, 0LL, WqkT, 1024, 0LL,
                                                QKb, 2048, 0LL, 1024, 1.0f, bqk, 1);
  // V^T[d][m] = sum_e WvT[d][e]*Xb[m][e] + bv[d]
  gemm_nt<<<dim3(128, 4, 1), 256, 0, stream>>>(WvT, 1024, 0LL, Xb, 1024, 0LL,
                                               VTb, 16384, 0LL, 1024, 1.0f, bv, 2);

  const float s = 0.044194173824159216f;  // 1/sqrt(512)
  // S1[q][k] = s * Q1[q].K1[k]   (Q1 = QKb cols 0..511, K1 = cols 1024..1535)
  gemm_nt<<<dim3(16, 16, 8), 256, 0, stream>>>(QKb, 2048, 4194304LL,
                                               QKb + 1024, 2048, 4194304LL,
                                               S1, 2048, 4194304LL, 512, s, nullptr, 0);
  // S2: Q2 = cols 512..1023, K2 = cols 1536..2047
  gemm_nt<<<dim3(16, 16, 8), 256, 0, stream>>>(QKb + 512, 2048, 4194304LL,
                                               QKb + 1536, 2048, 4194304LL,
                                               S2, 2048, 4194304LL, 512, s, nullptr, 0);

  row_stats<<<8192, 256, 0, stream>>>(S1, S2, statsF);
  apply_pv<<<dim3(64, 8), 256, 0, stream>>>(S1, S2, VTb, statsF, lam, Out);
}